// Round 1
// baseline (3899.368 us; speedup 1.0000x reference)
//
#include <hip/hip_runtime.h>
#include <hip/hip_bf16.h>

// Problem constants (match reference)
static constexpr int NN  = 100000;   // nodes
static constexpr int NE  = 1600000;  // edges
static constexpr int DIM = 128;
static constexpr int OC  = 10;
static constexpr float BN_EPS = 1e-5f;

__device__ __forceinline__ float4 f4fma(const float4 w, const float s, const float4 acc) {
    float4 r;
    r.x = fmaf(w.x, s, acc.x);
    r.y = fmaf(w.y, s, acc.y);
    r.z = fmaf(w.z, s, acc.z);
    r.w = fmaf(w.w, s, acc.w);
    return r;
}

// ---- degree / dinv -------------------------------------------------------
__global__ void k_deg(const int* __restrict__ dst, int* __restrict__ deg, int nE) {
    int e = blockIdx.x * 256 + threadIdx.x;
    if (e < nE) atomicAdd(&deg[dst[e]], 1);
}

__global__ void k_dinv(const int* __restrict__ deg, float* __restrict__ dinv, int n) {
    int i = blockIdx.x * 256 + threadIdx.x;
    if (i < n) dinv[i] = rsqrtf((float)deg[i] + 1.0f);   // deg includes self-loop (+1)
}

// ---- 128x128 matmul, optional fused BN+ReLU on the *input* ---------------
// Block: 256 threads. 32 rows per block. W staged in 64x128 LDS chunks (48KB total LDS).
template <bool FUSE_BN>
__global__ __launch_bounds__(256, 2)
void k_mm128(const float* __restrict__ in, const float* __restrict__ W,
             const float* __restrict__ cA, const float* __restrict__ cD,
             float* __restrict__ out)
{
    __shared__ float WL[64 * 128];   // 32 KB
    __shared__ float XS[32 * 128];   // 16 KB
    const int tid  = threadIdx.x;
    const int row0 = blockIdx.x * 32;

    // stage 32 input rows, applying BN+ReLU elementwise if fused
    {
        const float4* in4 = (const float4*)(in + (size_t)row0 * DIM);
        float4* XS4w = (float4*)XS;
        #pragma unroll
        for (int i = 0; i < 4; ++i) {
            int idx = tid + 256 * i;            // f4 index; col4 = idx & 31
            float4 v = in4[idx];
            if (FUSE_BN) {
                int c4 = (idx & 31) * 4;
                float4 a = *(const float4*)(cA + c4);
                float4 d = *(const float4*)(cD + c4);
                v.x = fmaxf(0.f, fmaf(v.x, a.x, d.x));
                v.y = fmaxf(0.f, fmaf(v.y, a.y, d.y));
                v.z = fmaxf(0.f, fmaf(v.z, a.z, d.z));
                v.w = fmaxf(0.f, fmaf(v.w, a.w, d.w));
            }
            XS4w[idx] = v;
        }
    }

    const int cg = tid & 31;   // col group: cols 4cg..4cg+3
    const int rg = tid >> 5;   // 0..7 -> rows rg*4..rg*4+3
    float4 acc0 = {0,0,0,0}, acc1 = {0,0,0,0}, acc2 = {0,0,0,0}, acc3 = {0,0,0,0};
    const float4* XS4 = (const float4*)XS;
    const float4* WL4 = (const float4*)WL;
    const float4* W4  = (const float4*)W;

    for (int kk = 0; kk < 128; kk += 64) {
        __syncthreads();     // XS visible (iter 0) / chunk-0 compute done (iter 1)
        #pragma unroll
        for (int i = 0; i < 8; ++i) {
            int idx = tid + 256 * i;
            ((float4*)WL)[idx] = W4[kk * 32 + idx];
        }
        __syncthreads();
        for (int k = 0; k < 64; k += 4) {
            float4 w0 = WL4[(k + 0) * 32 + cg];
            float4 w1 = WL4[(k + 1) * 32 + cg];
            float4 w2 = WL4[(k + 2) * 32 + cg];
            float4 w3 = WL4[(k + 3) * 32 + cg];
            int k4 = (kk + k) >> 2;
            float4 x0 = XS4[(rg * 4 + 0) * 32 + k4];
            float4 x1 = XS4[(rg * 4 + 1) * 32 + k4];
            float4 x2 = XS4[(rg * 4 + 2) * 32 + k4];
            float4 x3 = XS4[(rg * 4 + 3) * 32 + k4];
            acc0 = f4fma(w0, x0.x, f4fma(w1, x0.y, f4fma(w2, x0.z, f4fma(w3, x0.w, acc0))));
            acc1 = f4fma(w0, x1.x, f4fma(w1, x1.y, f4fma(w2, x1.z, f4fma(w3, x1.w, acc1))));
            acc2 = f4fma(w0, x2.x, f4fma(w1, x2.y, f4fma(w2, x2.z, f4fma(w3, x2.w, acc2))));
            acc3 = f4fma(w0, x3.x, f4fma(w1, x3.y, f4fma(w2, x3.z, f4fma(w3, x3.w, acc3))));
        }
    }

    float4* out4 = (float4*)(out + (size_t)row0 * DIM);
    out4[(rg * 4 + 0) * 32 + cg] = acc0;
    out4[(rg * 4 + 1) * 32 + cg] = acc1;
    out4[(rg * 4 + 2) * 32 + cg] = acc2;
    out4[(rg * 4 + 3) * 32 + cg] = acc3;
}

// ---- edge aggregation, 128 features: one wave per edge -------------------
__global__ __launch_bounds__(256)
void k_agg128(const float* __restrict__ h, const int* __restrict__ src,
              const int* __restrict__ dst, const float* __restrict__ dinv,
              float* __restrict__ agg, int nE)
{
    const int lane = threadIdx.x & 63;
    int wid = (blockIdx.x * 256 + threadIdx.x) >> 6;
    const int nW = (gridDim.x * 256) >> 6;
    for (int e = wid; e < nE; e += nW) {
        int s = src[e], t = dst[e];
        float norm = dinv[s] * dinv[t];
        float2 v = ((const float2*)h)[(size_t)s * 64 + lane];
        unsafeAtomicAdd(&agg[(size_t)t * 128 + lane * 2 + 0], v.x * norm);
        unsafeAtomicAdd(&agg[(size_t)t * 128 + lane * 2 + 1], v.y * norm);
    }
}

// ---- finalize (self-loop + bias) + BN statistics -------------------------
// Block: 256 threads = 128 cols x 2 row-halves; 128 rows per block.
__global__ __launch_bounds__(256)
void k_finalize_stats(float* __restrict__ agg, const float* __restrict__ h,
                      const float* __restrict__ dinv, const float* __restrict__ bias,
                      float* __restrict__ stats, int n)
{
    const int col  = threadIdx.x & 127;
    const int half = threadIdx.x >> 7;
    const int r0   = blockIdx.x * 128;
    const float b  = bias[col];
    float sum = 0.f, sq = 0.f;
    for (int i = half; i < 128; i += 2) {
        int r = r0 + i;
        if (r < n) {
            float di = dinv[r];
            size_t off = (size_t)r * 128 + col;
            float v = agg[off] + h[off] * di * di + b;
            agg[off] = v;
            sum += v;
            sq  += v * v;
        }
    }
    __shared__ float ls[256], lq[256];
    ls[threadIdx.x] = sum;
    lq[threadIdx.x] = sq;
    __syncthreads();
    if (half == 0) {
        sum += ls[threadIdx.x + 128];
        sq  += lq[threadIdx.x + 128];
        unsafeAtomicAdd(&stats[col],       sum);
        unsafeAtomicAdd(&stats[128 + col], sq);
    }
}

// ---- BN coefficients: v_norm = a*v + d -----------------------------------
__global__ void k_coef(const float* __restrict__ stats, const float* __restrict__ g,
                       const float* __restrict__ be, float* __restrict__ coef, float invN)
{
    int c = threadIdx.x;
    float mu  = stats[c] * invN;
    float var = stats[128 + c] * invN - mu * mu;
    float a = g[c] * rsqrtf(var + BN_EPS);
    coef[c]       = a;
    coef[128 + c] = be[c] - mu * a;
}

// ---- layer-2 matmul 128->10 with fused BN+ReLU on input ------------------
// Block: 128 threads, 32 rows/block. Cols padded to 16 in LDS.
__global__ __launch_bounds__(128)
void k_mm_l2(const float* __restrict__ in, const float* __restrict__ W2,
             const float* __restrict__ cA, const float* __restrict__ cD,
             float* __restrict__ out)
{
    __shared__ float WL[128 * 16];   // 8 KB (cols padded 10->16, zeros)
    __shared__ float XS[32 * 128];   // 16 KB
    const int tid  = threadIdx.x;
    const int row0 = blockIdx.x * 32;

    for (int idx = tid; idx < 128 * 16; idx += 128) {
        int k = idx >> 4, c = idx & 15;
        WL[idx] = (c < OC) ? W2[k * OC + c] : 0.0f;
    }
    {
        const float4* in4 = (const float4*)(in + (size_t)row0 * DIM);
        float4* XS4w = (float4*)XS;
        #pragma unroll
        for (int i = 0; i < 8; ++i) {
            int idx = tid + 128 * i;
            float4 v = in4[idx];
            int c4 = (idx & 31) * 4;
            float4 a = *(const float4*)(cA + c4);
            float4 d = *(const float4*)(cD + c4);
            v.x = fmaxf(0.f, fmaf(v.x, a.x, d.x));
            v.y = fmaxf(0.f, fmaf(v.y, a.y, d.y));
            v.z = fmaxf(0.f, fmaf(v.z, a.z, d.z));
            v.w = fmaxf(0.f, fmaf(v.w, a.w, d.w));
            XS4w[idx] = v;
        }
    }
    __syncthreads();

    const int cg = tid & 3;    // cols 4cg..4cg+3 (of 16 padded)
    const int rg = tid >> 2;   // row 0..31
    float4 acc = {0,0,0,0};
    const float4* XS4 = (const float4*)XS;
    const float4* WL4 = (const float4*)WL;
    for (int k = 0; k < 128; k += 4) {
        float4 w0 = WL4[(k + 0) * 4 + cg];
        float4 w1 = WL4[(k + 1) * 4 + cg];
        float4 w2 = WL4[(k + 2) * 4 + cg];
        float4 w3 = WL4[(k + 3) * 4 + cg];
        float4 x = XS4[rg * 32 + (k >> 2)];
        acc = f4fma(w0, x.x, f4fma(w1, x.y, f4fma(w2, x.z, f4fma(w3, x.w, acc))));
    }
    int row = row0 + rg;
    float av[4] = {acc.x, acc.y, acc.z, acc.w};
    #pragma unroll
    for (int j = 0; j < 4; ++j) {
        int c = cg * 4 + j;
        if (c < OC) out[(size_t)row * OC + c] = av[j];
    }
}

// ---- edge aggregation, 10 features: one thread per edge ------------------
__global__ __launch_bounds__(256)
void k_agg10(const float* __restrict__ C, const int* __restrict__ src,
             const int* __restrict__ dst, const float* __restrict__ dinv,
             float* __restrict__ out, int nE)
{
    int e = blockIdx.x * 256 + threadIdx.x;
    if (e >= nE) return;
    int s = src[e], t = dst[e];
    float norm = dinv[s] * dinv[t];
    const float* cs = C + (size_t)s * OC;
    float* od = out + (size_t)t * OC;
    #pragma unroll
    for (int c = 0; c < OC; ++c)
        unsafeAtomicAdd(&od[c], cs[c] * norm);
}

// ---- layer-2 finalize: out += C*dinv^2 + b2 ------------------------------
__global__ __launch_bounds__(256)
void k_fin_l2(float* __restrict__ out, const float* __restrict__ C,
              const float* __restrict__ dinv, const float* __restrict__ b2, int n)
{
    int i = blockIdx.x * 256 + threadIdx.x;
    if (i >= n * OC) return;
    int r = i / OC, c = i - r * OC;
    float di = dinv[r];
    out[i] += C[i] * di * di + b2[c];
}

extern "C" void kernel_launch(void* const* d_in, const int* in_sizes, int n_in,
                              void* d_out, int out_size, void* d_ws, size_t ws_size,
                              hipStream_t stream) {
    const float* x   = (const float*)d_in[0];
    const int*   ei  = (const int*)d_in[1];       // int32 (jax x64 disabled)
    const int*   srcv = ei;                        // row 0
    const int*   dstv = ei + NE;                   // row 1
    const float* W0  = (const float*)d_in[2];
    const float* b0  = (const float*)d_in[3];
    const float* g0  = (const float*)d_in[4];
    const float* be0 = (const float*)d_in[5];
    const float* W1  = (const float*)d_in[6];
    const float* b1  = (const float*)d_in[7];
    const float* g1  = (const float*)d_in[8];
    const float* be1 = (const float*)d_in[9];
    const float* W2  = (const float*)d_in[10];
    const float* b2  = (const float*)d_in[11];
    float* out = (float*)d_out;

    // workspace layout (floats): deg | dinv | A | B | C | stats | coef
    float* base  = (float*)d_ws;
    int*   deg   = (int*)base;
    float* dinv  = base + NN;
    float* A     = base + 2 * NN;                     // h (pre-BN matmul result)
    float* B     = A + (size_t)NN * DIM;              // agg -> v
    float* C     = B + (size_t)NN * DIM;              // layer-2 h2 (N x 10)
    float* stats = C + (size_t)NN * OC;               // 256: colsum | colsumsq
    float* coef  = stats + 256;                       // 256: a | d

    const float invN = 1.0f / (float)NN;

    // degree + dinv
    hipMemsetAsync(deg, 0, NN * sizeof(int), stream);
    k_deg<<<(NE + 255) / 256, 256, 0, stream>>>(dstv, deg, NE);
    k_dinv<<<(NN + 255) / 256, 256, 0, stream>>>(deg, dinv, NN);

    // ---- layer 0 ----
    k_mm128<false><<<NN / 32, 256, 0, stream>>>(x, W0, coef, coef + 128, A);
    hipMemsetAsync(B, 0, (size_t)NN * DIM * sizeof(float), stream);
    hipMemsetAsync(stats, 0, 256 * sizeof(float), stream);
    k_agg128<<<4096, 256, 0, stream>>>(A, srcv, dstv, dinv, B, NE);
    k_finalize_stats<<<(NN + 127) / 128, 256, 0, stream>>>(B, A, dinv, b0, stats, NN);
    k_coef<<<1, 128, 0, stream>>>(stats, g0, be0, coef, invN);

    // ---- layer 1 ----
    k_mm128<true><<<NN / 32, 256, 0, stream>>>(B, W1, coef, coef + 128, A);
    hipMemsetAsync(B, 0, (size_t)NN * DIM * sizeof(float), stream);
    hipMemsetAsync(stats, 0, 256 * sizeof(float), stream);
    k_agg128<<<4096, 256, 0, stream>>>(A, srcv, dstv, dinv, B, NE);
    k_finalize_stats<<<(NN + 127) / 128, 256, 0, stream>>>(B, A, dinv, b1, stats, NN);
    k_coef<<<1, 128, 0, stream>>>(stats, g1, be1, coef, invN);

    // ---- layer 2 (project to 10 dims FIRST, then aggregate cheap) ----
    k_mm_l2<<<NN / 32, 128, 0, stream>>>(B, W2, coef, coef + 128, C);
    hipMemsetAsync(out, 0, (size_t)NN * OC * sizeof(float), stream);
    k_agg10<<<(NE + 255) / 256, 256, 0, stream>>>(C, srcv, dstv, dinv, out, NE);
    k_fin_l2<<<(NN * OC + 255) / 256, 256, 0, stream>>>(out, C, dinv, b2, NN);
}

// Round 2
// 938.869 us; speedup vs baseline: 4.1533x; 4.1533x over previous
//
#include <hip/hip_runtime.h>
#include <hip/hip_bf16.h>

// Problem constants (match reference)
static constexpr int NN  = 100000;   // nodes
static constexpr int NE  = 1600000;  // edges
static constexpr int DIM = 128;
static constexpr int OC  = 10;
static constexpr int NB  = (NN + 255) / 256;   // 391 scan blocks
static constexpr float BN_EPS = 1e-5f;

__device__ __forceinline__ float4 f4fma(const float4 w, const float s, const float4 acc) {
    float4 r;
    r.x = fmaf(w.x, s, acc.x);
    r.y = fmaf(w.y, s, acc.y);
    r.z = fmaf(w.z, s, acc.z);
    r.w = fmaf(w.w, s, acc.w);
    return r;
}

// ---- degree / dinv -------------------------------------------------------
__global__ void k_deg(const int* __restrict__ dst, int* __restrict__ deg, int nE) {
    int e = blockIdx.x * 256 + threadIdx.x;
    if (e < nE) atomicAdd(&deg[dst[e]], 1);
}

__global__ void k_dinv(const int* __restrict__ deg, float* __restrict__ dinv, int n) {
    int i = blockIdx.x * 256 + threadIdx.x;
    if (i < n) dinv[i] = rsqrtf((float)deg[i] + 1.0f);   // deg includes self-loop (+1)
}

// ---- two-level exclusive scan: deg -> rowptr -----------------------------
__global__ void k_bsum(const int* __restrict__ deg, int* __restrict__ bsum) {
    __shared__ int s[256];
    int i = blockIdx.x * 256 + threadIdx.x;
    s[threadIdx.x] = (i < NN) ? deg[i] : 0;
    __syncthreads();
    for (int o = 128; o > 0; o >>= 1) {
        if (threadIdx.x < o) s[threadIdx.x] += s[threadIdx.x + o];
        __syncthreads();
    }
    if (threadIdx.x == 0) bsum[blockIdx.x] = s[0];
}

__global__ void k_bscan(const int* __restrict__ bsum, int* __restrict__ boff) {
    __shared__ int s[512];
    int t = threadIdx.x;
    int v = (t < NB) ? bsum[t] : 0;
    s[t] = v;
    __syncthreads();
    for (int o = 1; o < 512; o <<= 1) {
        int add = (t >= o) ? s[t - o] : 0;
        __syncthreads();
        s[t] += add;
        __syncthreads();
    }
    if (t < NB) boff[t] = s[t] - v;   // exclusive
}

// cursor may alias deg: deg[i] is read (by this thread) before cursor[i] write
__global__ void k_rowptr(const int* __restrict__ deg, const int* __restrict__ boff,
                         int* __restrict__ rowptr, int* __restrict__ cursor) {
    __shared__ int s[256];
    int t = threadIdx.x, i = blockIdx.x * 256 + t;
    int v = (i < NN) ? deg[i] : 0;
    s[t] = v;
    __syncthreads();
    for (int o = 1; o < 256; o <<= 1) {
        int add = (t >= o) ? s[t - o] : 0;
        __syncthreads();
        s[t] += add;
        __syncthreads();
    }
    if (i < NN) {
        int ex = boff[blockIdx.x] + s[t] - v;
        rowptr[i] = ex;
        cursor[i] = ex;
        if (i == NN - 1) rowptr[NN] = ex + v;
    }
}

__global__ void k_scatter(const int* __restrict__ src, const int* __restrict__ dst,
                          int* __restrict__ cursor, int* __restrict__ perm, int nE) {
    int e = blockIdx.x * 256 + threadIdx.x;
    if (e < nE) {
        int t = dst[e];
        int slot = atomicAdd(&cursor[t], 1);
        perm[slot] = src[e];
    }
}

// ---- 128x128 matmul, optional fused BN+ReLU on the *input* ---------------
template <bool FUSE_BN>
__global__ __launch_bounds__(256, 2)
void k_mm128(const float* __restrict__ in, const float* __restrict__ W,
             const float* __restrict__ cA, const float* __restrict__ cD,
             float* __restrict__ out)
{
    __shared__ float WL[64 * 128];   // 32 KB
    __shared__ float XS[32 * 128];   // 16 KB
    const int tid  = threadIdx.x;
    const int row0 = blockIdx.x * 32;

    {
        const float4* in4 = (const float4*)(in + (size_t)row0 * DIM);
        float4* XS4w = (float4*)XS;
        #pragma unroll
        for (int i = 0; i < 4; ++i) {
            int idx = tid + 256 * i;
            float4 v = in4[idx];
            if (FUSE_BN) {
                int c4 = (idx & 31) * 4;
                float4 a = *(const float4*)(cA + c4);
                float4 d = *(const float4*)(cD + c4);
                v.x = fmaxf(0.f, fmaf(v.x, a.x, d.x));
                v.y = fmaxf(0.f, fmaf(v.y, a.y, d.y));
                v.z = fmaxf(0.f, fmaf(v.z, a.z, d.z));
                v.w = fmaxf(0.f, fmaf(v.w, a.w, d.w));
            }
            XS4w[idx] = v;
        }
    }

    const int cg = tid & 31;
    const int rg = tid >> 5;
    float4 acc0 = {0,0,0,0}, acc1 = {0,0,0,0}, acc2 = {0,0,0,0}, acc3 = {0,0,0,0};
    const float4* XS4 = (const float4*)XS;
    const float4* WL4 = (const float4*)WL;
    const float4* W4  = (const float4*)W;

    for (int kk = 0; kk < 128; kk += 64) {
        __syncthreads();
        #pragma unroll
        for (int i = 0; i < 8; ++i) {
            int idx = tid + 256 * i;
            ((float4*)WL)[idx] = W4[kk * 32 + idx];
        }
        __syncthreads();
        for (int k = 0; k < 64; k += 4) {
            float4 w0 = WL4[(k + 0) * 32 + cg];
            float4 w1 = WL4[(k + 1) * 32 + cg];
            float4 w2 = WL4[(k + 2) * 32 + cg];
            float4 w3 = WL4[(k + 3) * 32 + cg];
            int k4 = (kk + k) >> 2;
            float4 x0 = XS4[(rg * 4 + 0) * 32 + k4];
            float4 x1 = XS4[(rg * 4 + 1) * 32 + k4];
            float4 x2 = XS4[(rg * 4 + 2) * 32 + k4];
            float4 x3 = XS4[(rg * 4 + 3) * 32 + k4];
            acc0 = f4fma(w0, x0.x, f4fma(w1, x0.y, f4fma(w2, x0.z, f4fma(w3, x0.w, acc0))));
            acc1 = f4fma(w0, x1.x, f4fma(w1, x1.y, f4fma(w2, x1.z, f4fma(w3, x1.w, acc1))));
            acc2 = f4fma(w0, x2.x, f4fma(w1, x2.y, f4fma(w2, x2.z, f4fma(w3, x2.w, acc2))));
            acc3 = f4fma(w0, x3.x, f4fma(w1, x3.y, f4fma(w2, x3.z, f4fma(w3, x3.w, acc3))));
        }
    }

    float4* out4 = (float4*)(out + (size_t)row0 * DIM);
    out4[(rg * 4 + 0) * 32 + cg] = acc0;
    out4[(rg * 4 + 1) * 32 + cg] = acc1;
    out4[(rg * 4 + 2) * 32 + cg] = acc2;
    out4[(rg * 4 + 3) * 32 + cg] = acc3;
}

// ---- CSR aggregation, 128 features: one wave per node --------------------
// acc = sum_e dinv[src_e] * h[src_e]; out = acc*dinv[n] + h[n]*dinv[n]^2 + bias
// Fused BN statistics (column sum / sumsq) via block reduce + 1 atomic/col.
template <bool STATS>
__global__ __launch_bounds__(256)
void k_agg_csr(const float* __restrict__ h, const int* __restrict__ rowptr,
               const int* __restrict__ perm, const float* __restrict__ dinv,
               const float* __restrict__ bias, float* __restrict__ outB,
               float* __restrict__ stats)
{
    const int lane = threadIdx.x & 63;
    const int w    = threadIdx.x >> 6;        // wave in block, 0..3
    const int wid  = blockIdx.x * 4 + w;
    const int nW   = gridDim.x * 4;
    const float2* h2 = (const float2*)h;

    float2 sum = {0.f, 0.f}, sq = {0.f, 0.f};

    for (int n = wid; n < NN; n += nW) {
        int beg = rowptr[n], end = rowptr[n + 1];
        float2 acc = {0.f, 0.f};
        for (int j = beg; j < end; j += 64) {
            int nav = end - j; if (nav > 64) nav = 64;
            int idx = j + (lane < nav ? lane : nav - 1);
            int sv  = perm[idx];        // coalesced preload of up to 64 edges
            float dv = dinv[sv];
            for (int i = 0; i < nav; ++i) {
                int   s  = __shfl(sv, i);
                float nm = __shfl(dv, i);
                float2 v = h2[(size_t)s * 64 + lane];
                acc.x = fmaf(v.x, nm, acc.x);
                acc.y = fmaf(v.y, nm, acc.y);
            }
        }
        float di = dinv[n];
        float2 hv = h2[(size_t)n * 64 + lane];
        float bx = bias[2 * lane], by = bias[2 * lane + 1];
        float2 v;
        v.x = fmaf(acc.x, di, fmaf(hv.x, di * di, bx));
        v.y = fmaf(acc.y, di, fmaf(hv.y, di * di, by));
        ((float2*)outB)[(size_t)n * 64 + lane] = v;
        if (STATS) {
            sum.x += v.x; sum.y += v.y;
            sq.x  = fmaf(v.x, v.x, sq.x);
            sq.y  = fmaf(v.y, v.y, sq.y);
        }
    }

    if (STATS) {
        __shared__ float ls[4][128];
        __shared__ float lq[4][128];
        ls[w][2 * lane]     = sum.x;
        ls[w][2 * lane + 1] = sum.y;
        lq[w][2 * lane]     = sq.x;
        lq[w][2 * lane + 1] = sq.y;
        __syncthreads();
        int t = threadIdx.x;
        if (t < 128) {
            float a = ls[0][t] + ls[1][t] + ls[2][t] + ls[3][t];
            float b = lq[0][t] + lq[1][t] + lq[2][t] + lq[3][t];
            unsafeAtomicAdd(&stats[t], a);
            unsafeAtomicAdd(&stats[128 + t], b);
        }
    }
}

// ---- BN coefficients: v_norm = a*v + d -----------------------------------
__global__ void k_coef(const float* __restrict__ stats, const float* __restrict__ g,
                       const float* __restrict__ be, float* __restrict__ coef, float invN)
{
    int c = threadIdx.x;
    float mu  = stats[c] * invN;
    float var = stats[128 + c] * invN - mu * mu;
    float a = g[c] * rsqrtf(var + BN_EPS);
    coef[c]       = a;
    coef[128 + c] = be[c] - mu * a;
}

// ---- layer-2 matmul 128->10 (writes 16-col padded C) ---------------------
__global__ __launch_bounds__(128)
void k_mm_l2(const float* __restrict__ in, const float* __restrict__ W2,
             const float* __restrict__ cA, const float* __restrict__ cD,
             float* __restrict__ C16)
{
    __shared__ float WL[128 * 16];   // cols padded 10->16 with zeros
    __shared__ float XS[32 * 128];
    const int tid  = threadIdx.x;
    const int row0 = blockIdx.x * 32;

    for (int idx = tid; idx < 128 * 16; idx += 128) {
        int k = idx >> 4, c = idx & 15;
        WL[idx] = (c < OC) ? W2[k * OC + c] : 0.0f;
    }
    {
        const float4* in4 = (const float4*)(in + (size_t)row0 * DIM);
        float4* XS4w = (float4*)XS;
        #pragma unroll
        for (int i = 0; i < 8; ++i) {
            int idx = tid + 128 * i;
            float4 v = in4[idx];
            int c4 = (idx & 31) * 4;
            float4 a = *(const float4*)(cA + c4);
            float4 d = *(const float4*)(cD + c4);
            v.x = fmaxf(0.f, fmaf(v.x, a.x, d.x));
            v.y = fmaxf(0.f, fmaf(v.y, a.y, d.y));
            v.z = fmaxf(0.f, fmaf(v.z, a.z, d.z));
            v.w = fmaxf(0.f, fmaf(v.w, a.w, d.w));
            XS4w[idx] = v;
        }
    }
    __syncthreads();

    const int cg = tid & 3;    // float4 group of 16 padded cols
    const int rg = tid >> 2;   // row 0..31
    float4 acc = {0,0,0,0};
    const float4* XS4 = (const float4*)XS;
    const float4* WL4 = (const float4*)WL;
    for (int k = 0; k < 128; k += 4) {
        float4 w0 = WL4[(k + 0) * 4 + cg];
        float4 w1 = WL4[(k + 1) * 4 + cg];
        float4 w2 = WL4[(k + 2) * 4 + cg];
        float4 w3 = WL4[(k + 3) * 4 + cg];
        float4 x = XS4[rg * 32 + (k >> 2)];
        acc = f4fma(w0, x.x, f4fma(w1, x.y, f4fma(w2, x.z, f4fma(w3, x.w, acc))));
    }
    ((float4*)C16)[((size_t)row0 + rg) * 4 + cg] = acc;   // padded cols are 0
}

// ---- CSR aggregation, 10 features: 16 lanes per node ---------------------
__global__ __launch_bounds__(256)
void k_agg10(const float* __restrict__ C16, const int* __restrict__ rowptr,
             const int* __restrict__ perm, const float* __restrict__ dinv,
             const float* __restrict__ b2, float* __restrict__ out)
{
    const int lane = threadIdx.x & 63;
    const int sub  = lane >> 4, sl = lane & 15;
    const int wid  = (blockIdx.x * 256 + threadIdx.x) >> 6;
    const int nW   = gridDim.x * 4;
    for (int n4 = wid * 4; n4 < NN; n4 += nW * 4) {
        int n = n4 + sub;                       // NN % 4 == 0 -> always < NN
        int beg = rowptr[n], end = rowptr[n + 1];
        float acc = 0.f;
        for (int j = beg; j < end; ++j) {
            int s = perm[j];
            float nm = dinv[s];
            acc = fmaf(C16[(size_t)s * 16 + sl], nm, acc);
        }
        float di = dinv[n];
        float v = fmaf(acc, di, C16[(size_t)n * 16 + sl] * di * di);
        if (sl < OC) out[(size_t)n * OC + sl] = v + b2[sl];
    }
}

extern "C" void kernel_launch(void* const* d_in, const int* in_sizes, int n_in,
                              void* d_out, int out_size, void* d_ws, size_t ws_size,
                              hipStream_t stream) {
    const float* x    = (const float*)d_in[0];
    const int*   ei   = (const int*)d_in[1];
    const int*   srcv = ei;          // row 0
    const int*   dstv = ei + NE;     // row 1
    const float* W0  = (const float*)d_in[2];
    const float* b0  = (const float*)d_in[3];
    const float* g0  = (const float*)d_in[4];
    const float* be0 = (const float*)d_in[5];
    const float* W1  = (const float*)d_in[6];
    const float* b1  = (const float*)d_in[7];
    const float* g1  = (const float*)d_in[8];
    const float* be1 = (const float*)d_in[9];
    const float* W2  = (const float*)d_in[10];
    const float* b2  = (const float*)d_in[11];
    float* out = (float*)d_out;

    // workspace layout (4-byte words), ~110 MB total
    float* base   = (float*)d_ws;
    int*   deg    = (int*)base;                 // [0, NN)          (cursor aliases)
    float* dinv   = base + NN;                  // [NN, 2NN)
    int*   rowptr = (int*)(base + 2 * NN);      // NN+1
    int*   bsum   = (int*)(base + 300004);      // 512
    int*   boff   = (int*)(base + 300516);      // 512
    float* stats  = base + 301028;              // 512 (L0: +0, L1: +256)
    float* coef   = base + 301540;              // 512 (L0: +0, L1: +256)
    float* A      = base + 302052;              // NN*128
    float* B      = A + (size_t)NN * DIM;       // NN*128
    int*   perm   = (int*)(B + (size_t)NN * DIM); // NE
    float* C16    = A;                          // layer-2 h2, aliases A (dead then)
    int*   cursor = deg;

    const float invN = 1.0f / (float)NN;

    hipMemsetAsync(deg, 0, NN * sizeof(int), stream);
    hipMemsetAsync(stats, 0, 512 * sizeof(float), stream);

    // CSR build
    k_deg<<<(NE + 255) / 256, 256, 0, stream>>>(dstv, deg, NE);
    k_dinv<<<NB, 256, 0, stream>>>(deg, dinv, NN);
    k_bsum<<<NB, 256, 0, stream>>>(deg, bsum);
    k_bscan<<<1, 512, 0, stream>>>(bsum, boff);
    k_rowptr<<<NB, 256, 0, stream>>>(deg, boff, rowptr, cursor);
    k_scatter<<<(NE + 255) / 256, 256, 0, stream>>>(srcv, dstv, cursor, perm, NE);

    // ---- layer 0 ----
    k_mm128<false><<<NN / 32, 256, 0, stream>>>(x, W0, coef, coef + 128, A);
    k_agg_csr<true><<<2048, 256, 0, stream>>>(A, rowptr, perm, dinv, b0, B, stats);
    k_coef<<<1, 128, 0, stream>>>(stats, g0, be0, coef, invN);

    // ---- layer 1 ----
    k_mm128<true><<<NN / 32, 256, 0, stream>>>(B, W1, coef, coef + 128, A);
    k_agg_csr<true><<<2048, 256, 0, stream>>>(A, rowptr, perm, dinv, b1, B, stats + 256);
    k_coef<<<1, 128, 0, stream>>>(stats + 256, g1, be1, coef + 256, invN);

    // ---- layer 2: project to 10 dims first, aggregate cheap ----
    k_mm_l2<<<NN / 32, 128, 0, stream>>>(B, W2, coef + 256, coef + 384, C16);
    k_agg10<<<1024, 256, 0, stream>>>(C16, rowptr, perm, dinv, b2, out);
}

// Round 3
// 802.023 us; speedup vs baseline: 4.8619x; 1.1706x over previous
//
#include <hip/hip_runtime.h>
#include <hip/hip_bf16.h>

// Problem constants (match reference)
static constexpr int NN  = 100000;   // nodes
static constexpr int NE  = 1600000;  // edges
static constexpr int DIM = 128;
static constexpr int OC  = 10;
static constexpr int NB  = (NN + 255) / 256;   // 391 scan blocks
static constexpr float BN_EPS = 1e-5f;

typedef unsigned short ushortT;

__device__ __forceinline__ float bf2f(ushortT u) {
    union { unsigned int i; float f; } c;
    c.i = ((unsigned int)u) << 16;
    return c.f;
}

__device__ __forceinline__ ushortT f2bf(float f) {
    union { float f; unsigned int i; } c;
    c.f = f;
    unsigned int r = c.i + 0x7FFFu + ((c.i >> 16) & 1u);   // RNE
    return (ushortT)(r >> 16);
}

__device__ __forceinline__ float4 f4fma(const float4 w, const float s, const float4 acc) {
    float4 r;
    r.x = fmaf(w.x, s, acc.x);
    r.y = fmaf(w.y, s, acc.y);
    r.z = fmaf(w.z, s, acc.z);
    r.w = fmaf(w.w, s, acc.w);
    return r;
}

// ---- degree / dinv -------------------------------------------------------
__global__ void k_deg(const int* __restrict__ dst, int* __restrict__ deg, int nE) {
    int e = blockIdx.x * 256 + threadIdx.x;
    if (e < nE) atomicAdd(&deg[dst[e]], 1);
}

__global__ void k_dinv(const int* __restrict__ deg, float* __restrict__ dinv, int n) {
    int i = blockIdx.x * 256 + threadIdx.x;
    if (i < n) dinv[i] = rsqrtf((float)deg[i] + 1.0f);   // deg includes self-loop (+1)
}

// ---- two-level exclusive scan: deg -> rowptr -----------------------------
__global__ void k_bsum(const int* __restrict__ deg, int* __restrict__ bsum) {
    __shared__ int s[256];
    int i = blockIdx.x * 256 + threadIdx.x;
    s[threadIdx.x] = (i < NN) ? deg[i] : 0;
    __syncthreads();
    for (int o = 128; o > 0; o >>= 1) {
        if (threadIdx.x < o) s[threadIdx.x] += s[threadIdx.x + o];
        __syncthreads();
    }
    if (threadIdx.x == 0) bsum[blockIdx.x] = s[0];
}

__global__ void k_bscan(const int* __restrict__ bsum, int* __restrict__ boff) {
    __shared__ int s[512];
    int t = threadIdx.x;
    int v = (t < NB) ? bsum[t] : 0;
    s[t] = v;
    __syncthreads();
    for (int o = 1; o < 512; o <<= 1) {
        int add = (t >= o) ? s[t - o] : 0;
        __syncthreads();
        s[t] += add;
        __syncthreads();
    }
    if (t < NB) boff[t] = s[t] - v;   // exclusive
}

// cursor may alias deg: deg[i] is read (by this thread) before cursor[i] write
__global__ void k_rowptr(const int* __restrict__ deg, const int* __restrict__ boff,
                         int* __restrict__ rowptr, int* __restrict__ cursor) {
    __shared__ int s[256];
    int t = threadIdx.x, i = blockIdx.x * 256 + t;
    int v = (i < NN) ? deg[i] : 0;
    s[t] = v;
    __syncthreads();
    for (int o = 1; o < 256; o <<= 1) {
        int add = (t >= o) ? s[t - o] : 0;
        __syncthreads();
        s[t] += add;
        __syncthreads();
    }
    if (i < NN) {
        int ex = boff[blockIdx.x] + s[t] - v;
        rowptr[i] = ex;
        cursor[i] = ex;
        if (i == NN - 1) rowptr[NN] = ex + v;
    }
}

// scatter edges into CSR slots, packing {src, dinv[src]} (8B) per edge
__global__ void k_scatter(const int* __restrict__ src, const int* __restrict__ dst,
                          const float* __restrict__ dinv, int* __restrict__ cursor,
                          int2* __restrict__ edata, int nE) {
    int e = blockIdx.x * 256 + threadIdx.x;
    if (e < nE) {
        int t = dst[e], s = src[e];
        int slot = atomicAdd(&cursor[t], 1);
        edata[slot] = make_int2(s, __float_as_int(dinv[s]));
    }
}

// ---- 128x128 matmul, fused BN+ReLU on input, bf16 output -----------------
template <bool FUSE_BN>
__global__ __launch_bounds__(256, 2)
void k_mm128(const float* __restrict__ in, const float* __restrict__ W,
             const float* __restrict__ cA, const float* __restrict__ cD,
             ushortT* __restrict__ outb)
{
    __shared__ float WL[64 * 128];   // 32 KB
    __shared__ float XS[32 * 128];   // 16 KB
    const int tid  = threadIdx.x;
    const int row0 = blockIdx.x * 32;

    {
        const float4* in4 = (const float4*)(in + (size_t)row0 * DIM);
        float4* XS4w = (float4*)XS;
        #pragma unroll
        for (int i = 0; i < 4; ++i) {
            int idx = tid + 256 * i;
            float4 v = in4[idx];
            if (FUSE_BN) {
                int c4 = (idx & 31) * 4;
                float4 a = *(const float4*)(cA + c4);
                float4 d = *(const float4*)(cD + c4);
                v.x = fmaxf(0.f, fmaf(v.x, a.x, d.x));
                v.y = fmaxf(0.f, fmaf(v.y, a.y, d.y));
                v.z = fmaxf(0.f, fmaf(v.z, a.z, d.z));
                v.w = fmaxf(0.f, fmaf(v.w, a.w, d.w));
            }
            XS4w[idx] = v;
        }
    }

    const int cg = tid & 31;
    const int rg = tid >> 5;
    float4 acc0 = {0,0,0,0}, acc1 = {0,0,0,0}, acc2 = {0,0,0,0}, acc3 = {0,0,0,0};
    const float4* XS4 = (const float4*)XS;
    const float4* WL4 = (const float4*)WL;
    const float4* W4  = (const float4*)W;

    for (int kk = 0; kk < 128; kk += 64) {
        __syncthreads();
        #pragma unroll
        for (int i = 0; i < 8; ++i) {
            int idx = tid + 256 * i;
            ((float4*)WL)[idx] = W4[kk * 32 + idx];
        }
        __syncthreads();
        for (int k = 0; k < 64; k += 4) {
            float4 w0 = WL4[(k + 0) * 32 + cg];
            float4 w1 = WL4[(k + 1) * 32 + cg];
            float4 w2 = WL4[(k + 2) * 32 + cg];
            float4 w3 = WL4[(k + 3) * 32 + cg];
            int k4 = (kk + k) >> 2;
            float4 x0 = XS4[(rg * 4 + 0) * 32 + k4];
            float4 x1 = XS4[(rg * 4 + 1) * 32 + k4];
            float4 x2 = XS4[(rg * 4 + 2) * 32 + k4];
            float4 x3 = XS4[(rg * 4 + 3) * 32 + k4];
            acc0 = f4fma(w0, x0.x, f4fma(w1, x0.y, f4fma(w2, x0.z, f4fma(w3, x0.w, acc0))));
            acc1 = f4fma(w0, x1.x, f4fma(w1, x1.y, f4fma(w2, x1.z, f4fma(w3, x1.w, acc1))));
            acc2 = f4fma(w0, x2.x, f4fma(w1, x2.y, f4fma(w2, x2.z, f4fma(w3, x2.w, acc2))));
            acc3 = f4fma(w0, x3.x, f4fma(w1, x3.y, f4fma(w2, x3.z, f4fma(w3, x3.w, acc3))));
        }
    }

    float4 accs[4] = {acc0, acc1, acc2, acc3};
    #pragma unroll
    for (int i = 0; i < 4; ++i) {
        ushort4 o;
        o.x = f2bf(accs[i].x);
        o.y = f2bf(accs[i].y);
        o.z = f2bf(accs[i].z);
        o.w = f2bf(accs[i].w);
        ((ushort4*)(outb + (size_t)(row0 + rg * 4 + i) * DIM))[cg] = o;
    }
}

// ---- CSR aggregation, 128 features (bf16 rows), one wave per node --------
// acc = sum_e dinv[src_e]*h[src_e]; out = acc*dinv[n] + h[n]*dinv[n]^2 + bias
template <bool STATS>
__global__ __launch_bounds__(256)
void k_agg_csr(const ushortT* __restrict__ hb, const int* __restrict__ rowptr,
               const int2* __restrict__ edata, const float* __restrict__ dinv,
               const float* __restrict__ bias, float* __restrict__ outB,
               float* __restrict__ stats)
{
    const int lane = threadIdx.x & 63;
    const int w    = threadIdx.x >> 6;        // wave in block, 0..3
    const int wid  = blockIdx.x * 4 + w;
    const int nW   = gridDim.x * 4;
    const ushort2* h2 = (const ushort2*)hb;   // 64 x ushort2 per row

    float2 sum = {0.f, 0.f}, sq = {0.f, 0.f};

    for (int n = wid; n < NN; n += nW) {
        int beg = rowptr[n], end = rowptr[n + 1];
        float2 a0 = {0.f, 0.f}, a1 = {0.f, 0.f};
        for (int j = beg; j < end; j += 64) {
            int nav = end - j; if (nav > 64) nav = 64;
            int idx = j + (lane < nav ? lane : nav - 1);
            int2 ed = edata[idx];             // coalesced preload of up to 64 edges
            int   sv = ed.x;
            float wv = __int_as_float(ed.y);
            int i = 0;
            for (; i + 4 <= nav; i += 4) {
                int   s0 = __shfl(sv, i + 0), s1 = __shfl(sv, i + 1);
                int   s2 = __shfl(sv, i + 2), s3 = __shfl(sv, i + 3);
                float w0 = __shfl(wv, i + 0), w1 = __shfl(wv, i + 1);
                float w2 = __shfl(wv, i + 2), w3 = __shfl(wv, i + 3);
                ushort2 u0 = h2[(size_t)s0 * 64 + lane];
                ushort2 u1 = h2[(size_t)s1 * 64 + lane];
                ushort2 u2 = h2[(size_t)s2 * 64 + lane];
                ushort2 u3 = h2[(size_t)s3 * 64 + lane];
                a0.x = fmaf(bf2f(u0.x), w0, a0.x); a0.y = fmaf(bf2f(u0.y), w0, a0.y);
                a1.x = fmaf(bf2f(u1.x), w1, a1.x); a1.y = fmaf(bf2f(u1.y), w1, a1.y);
                a0.x = fmaf(bf2f(u2.x), w2, a0.x); a0.y = fmaf(bf2f(u2.y), w2, a0.y);
                a1.x = fmaf(bf2f(u3.x), w3, a1.x); a1.y = fmaf(bf2f(u3.y), w3, a1.y);
            }
            for (; i < nav; ++i) {
                int   s0 = __shfl(sv, i);
                float w0 = __shfl(wv, i);
                ushort2 u0 = h2[(size_t)s0 * 64 + lane];
                a0.x = fmaf(bf2f(u0.x), w0, a0.x); a0.y = fmaf(bf2f(u0.y), w0, a0.y);
            }
        }
        float di = dinv[n];
        ushort2 hu = h2[(size_t)n * 64 + lane];
        float2 v;
        v.x = fmaf(a0.x + a1.x, di, fmaf(bf2f(hu.x), di * di, bias[2 * lane]));
        v.y = fmaf(a0.y + a1.y, di, fmaf(bf2f(hu.y), di * di, bias[2 * lane + 1]));
        ((float2*)outB)[(size_t)n * 64 + lane] = v;
        if (STATS) {
            sum.x += v.x; sum.y += v.y;
            sq.x = fmaf(v.x, v.x, sq.x);
            sq.y = fmaf(v.y, v.y, sq.y);
        }
    }

    if (STATS) {
        __shared__ float ls[4][128];
        __shared__ float lq[4][128];
        ls[w][2 * lane]     = sum.x;
        ls[w][2 * lane + 1] = sum.y;
        lq[w][2 * lane]     = sq.x;
        lq[w][2 * lane + 1] = sq.y;
        __syncthreads();
        int t = threadIdx.x;
        if (t < 128) {
            float a = ls[0][t] + ls[1][t] + ls[2][t] + ls[3][t];
            float b = lq[0][t] + lq[1][t] + lq[2][t] + lq[3][t];
            unsafeAtomicAdd(&stats[t], a);
            unsafeAtomicAdd(&stats[128 + t], b);
        }
    }
}

// ---- BN coefficients: v_norm = a*v + d -----------------------------------
__global__ void k_coef(const float* __restrict__ stats, const float* __restrict__ g,
                       const float* __restrict__ be, float* __restrict__ coef, float invN)
{
    int c = threadIdx.x;
    float mu  = stats[c] * invN;
    float var = stats[128 + c] * invN - mu * mu;
    float a = g[c] * rsqrtf(var + BN_EPS);
    coef[c]       = a;
    coef[128 + c] = be[c] - mu * a;
}

// ---- layer-2 matmul 128->10 (writes 16-col padded C, fp32) ---------------
__global__ __launch_bounds__(128)
void k_mm_l2(const float* __restrict__ in, const float* __restrict__ W2,
             const float* __restrict__ cA, const float* __restrict__ cD,
             float* __restrict__ C16)
{
    __shared__ float WL[128 * 16];   // cols padded 10->16 with zeros
    __shared__ float XS[32 * 128];
    const int tid  = threadIdx.x;
    const int row0 = blockIdx.x * 32;

    for (int idx = tid; idx < 128 * 16; idx += 128) {
        int k = idx >> 4, c = idx & 15;
        WL[idx] = (c < OC) ? W2[k * OC + c] : 0.0f;
    }
    {
        const float4* in4 = (const float4*)(in + (size_t)row0 * DIM);
        float4* XS4w = (float4*)XS;
        #pragma unroll
        for (int i = 0; i < 8; ++i) {
            int idx = tid + 128 * i;
            float4 v = in4[idx];
            int c4 = (idx & 31) * 4;
            float4 a = *(const float4*)(cA + c4);
            float4 d = *(const float4*)(cD + c4);
            v.x = fmaxf(0.f, fmaf(v.x, a.x, d.x));
            v.y = fmaxf(0.f, fmaf(v.y, a.y, d.y));
            v.z = fmaxf(0.f, fmaf(v.z, a.z, d.z));
            v.w = fmaxf(0.f, fmaf(v.w, a.w, d.w));
            XS4w[idx] = v;
        }
    }
    __syncthreads();

    const int cg = tid & 3;
    const int rg = tid >> 2;
    float4 acc = {0,0,0,0};
    const float4* XS4 = (const float4*)XS;
    const float4* WL4 = (const float4*)WL;
    for (int k = 0; k < 128; k += 4) {
        float4 w0 = WL4[(k + 0) * 4 + cg];
        float4 w1 = WL4[(k + 1) * 4 + cg];
        float4 w2 = WL4[(k + 2) * 4 + cg];
        float4 w3 = WL4[(k + 3) * 4 + cg];
        float4 x = XS4[rg * 32 + (k >> 2)];
        acc = f4fma(w0, x.x, f4fma(w1, x.y, f4fma(w2, x.z, f4fma(w3, x.w, acc))));
    }
    ((float4*)C16)[((size_t)row0 + rg) * 4 + cg] = acc;   // padded cols are 0
}

// ---- CSR aggregation, 10 features: 16 lanes per node ---------------------
__global__ __launch_bounds__(256)
void k_agg10(const float* __restrict__ C16, const int* __restrict__ rowptr,
             const int2* __restrict__ edata, const float* __restrict__ dinv,
             const float* __restrict__ b2, float* __restrict__ out)
{
    const int lane = threadIdx.x & 63;
    const int sub  = lane >> 4, sl = lane & 15;
    const int wid  = (blockIdx.x * 256 + threadIdx.x) >> 6;
    const int nW   = gridDim.x * 4;
    for (int n4 = wid * 4; n4 < NN; n4 += nW * 4) {
        int n = n4 + sub;                       // NN % 4 == 0 -> always < NN
        int beg = rowptr[n], end = rowptr[n + 1];
        float acc = 0.f;
        for (int j = beg; j < end; ++j) {
            int2 ed = edata[j];
            acc = fmaf(C16[(size_t)ed.x * 16 + sl], __int_as_float(ed.y), acc);
        }
        float di = dinv[n];
        float v = fmaf(acc, di, C16[(size_t)n * 16 + sl] * di * di);
        if (sl < OC) out[(size_t)n * OC + sl] = v + b2[sl];
    }
}

extern "C" void kernel_launch(void* const* d_in, const int* in_sizes, int n_in,
                              void* d_out, int out_size, void* d_ws, size_t ws_size,
                              hipStream_t stream) {
    const float* x    = (const float*)d_in[0];
    const int*   ei   = (const int*)d_in[1];
    const int*   srcv = ei;          // row 0
    const int*   dstv = ei + NE;     // row 1
    const float* W0  = (const float*)d_in[2];
    const float* b0  = (const float*)d_in[3];
    const float* g0  = (const float*)d_in[4];
    const float* be0 = (const float*)d_in[5];
    const float* W1  = (const float*)d_in[6];
    const float* b1  = (const float*)d_in[7];
    const float* g1  = (const float*)d_in[8];
    const float* be1 = (const float*)d_in[9];
    const float* W2  = (const float*)d_in[10];
    const float* b2  = (const float*)d_in[11];
    float* out = (float*)d_out;

    // workspace layout (4-byte words), ~91 MB total
    float* base   = (float*)d_ws;
    int*   deg    = (int*)base;                    // [0, NN)  (cursor aliases)
    float* dinv   = base + NN;                     // [NN, 2NN)
    int*   rowptr = (int*)(base + 2 * NN);         // NN+1
    int*   bsum   = (int*)(base + 300004);         // 512
    int*   boff   = (int*)(base + 300516);         // 512
    float* stats  = base + 301028;                 // 512 (L0: +0, L1: +256)
    float* coef   = base + 301540;                 // 512 (L0: +0, L1: +256)
    ushortT* A_bf = (ushortT*)(base + 302052);     // NN*128 bf16 = NN*64 words
    float* B      = base + 302052 + (size_t)NN * 64;        // NN*128 fp32
    int2*  edata  = (int2*)(B + (size_t)NN * DIM);          // NE * 8B
    float* C16    = (float*)A_bf;                  // layer-2 h2 (aliases A_bf, dead then)
    int*   cursor = deg;

    const float invN = 1.0f / (float)NN;

    hipMemsetAsync(deg, 0, NN * sizeof(int), stream);
    hipMemsetAsync(stats, 0, 512 * sizeof(float), stream);

    // CSR build
    k_deg<<<(NE + 255) / 256, 256, 0, stream>>>(dstv, deg, NE);
    k_dinv<<<NB, 256, 0, stream>>>(deg, dinv, NN);
    k_bsum<<<NB, 256, 0, stream>>>(deg, bsum);
    k_bscan<<<1, 512, 0, stream>>>(bsum, boff);
    k_rowptr<<<NB, 256, 0, stream>>>(deg, boff, rowptr, cursor);
    k_scatter<<<(NE + 255) / 256, 256, 0, stream>>>(srcv, dstv, dinv, cursor, edata, NE);

    // ---- layer 0 ----
    k_mm128<false><<<NN / 32, 256, 0, stream>>>(x, W0, coef, coef + 128, A_bf);
    k_agg_csr<true><<<2048, 256, 0, stream>>>(A_bf, rowptr, edata, dinv, b0, B, stats);
    k_coef<<<1, 128, 0, stream>>>(stats, g0, be0, coef, invN);

    // ---- layer 1 ----
    k_mm128<true><<<NN / 32, 256, 0, stream>>>(B, W1, coef, coef + 128, A_bf);
    k_agg_csr<true><<<2048, 256, 0, stream>>>(A_bf, rowptr, edata, dinv, b1, B, stats + 256);
    k_coef<<<1, 128, 0, stream>>>(stats + 256, g1, be1, coef + 256, invN);

    // ---- layer 2: project to 10 dims first, aggregate cheap ----
    k_mm_l2<<<NN / 32, 128, 0, stream>>>(B, W2, coef + 256, coef + 384, C16);
    k_agg10<<<1024, 256, 0, stream>>>(C16, rowptr, edata, dinv, b2, out);
}